// Round 1
// baseline (1750.798 us; speedup 1.0000x reference)
//
#include <hip/hip_runtime.h>
#include <hip/hip_bf16.h>
#include <cstdint>
#include <cstddef>

// Problem constants
#define SEQLEN   2048
#define HIDDEN   2048
#define INTER    4096
#define NHEADS   64
#define NSTATE   64
#define CONVD    4224          // INTER + 2*64
#define LDPROJ   8448          // PROJ (8384) padded to 128-multiple

typedef __attribute__((ext_vector_type(8))) short bf16x8_t;
typedef __attribute__((ext_vector_type(4))) float f32x4_t;

__device__ __forceinline__ void cp16(void* lds, const void* g) {
    __builtin_amdgcn_global_load_lds(
        (const __attribute__((address_space(1))) unsigned int*)g,
        (__attribute__((address_space(3))) unsigned int*)lds, 16, 0, 0);
}

// ---------------- split fp32 -> bf16 (hi, lo) ----------------
__global__ void k_split(const float* __restrict__ in, unsigned short* __restrict__ hi,
                        unsigned short* __restrict__ lo, long nvalid, long ntotal) {
    long i = (long)blockIdx.x * 256 + threadIdx.x;
    if (i >= ntotal) return;
    float x = (i < nvalid) ? in[i] : 0.0f;   // zero-pad region beyond nvalid
    __hip_bfloat16 h = __float2bfloat16(x);
    float hf = __bfloat162float(h);
    __hip_bfloat16 l = __float2bfloat16(x - hf);
    hi[i] = *reinterpret_cast<unsigned short*>(&h);
    lo[i] = *reinterpret_cast<unsigned short*>(&l);
}

// ---------------- split-bf16 GEMM: C[M,N] = A[M,K] * B[N,K]^T (fp32-accurate) --------
// 128x128 tile per block, 4 waves in 2x2, each wave 64x64 via 4x4 mfma_16x16x32 tiles.
// 3 MFMAs per tile per k-step: ah*bh + ah*bl + al*bh  (Ootomo split, ~2^-18 rel err)
__global__ __launch_bounds__(256, 2)
void k_gemm_split(const unsigned short* __restrict__ Ah, const unsigned short* __restrict__ Al,
                  const unsigned short* __restrict__ Bh, const unsigned short* __restrict__ Bl,
                  float* __restrict__ C, int K, int ldc) {
    __shared__ unsigned short sA[2][128 * 32];
    __shared__ unsigned short sB[2][128 * 32];

    const int tid  = threadIdx.x;
    const int lane = tid & 63;
    const int w    = tid >> 6;       // wave 0..3
    const int wm   = w >> 1, wn = w & 1;
    const long bm  = (long)blockIdx.y * 128;
    const long bn  = (long)blockIdx.x * 128;

    f32x4_t acc[4][4];
#pragma unroll
    for (int i = 0; i < 4; ++i)
#pragma unroll
        for (int j = 0; j < 4; ++j) acc[i][j] = (f32x4_t){0.f, 0.f, 0.f, 0.f};

    const int l4 = lane >> 2;          // 0..15 row-in-chunk
    const int c8 = (lane & 3) << 3;    // k element offset 0/8/16/24
    const int ar = lane & 15;          // fragment row
    const int kq = (lane >> 4) << 3;   // fragment k offset (quad*8)

    for (int k0 = 0; k0 < K; k0 += 32) {
        // stage A/B hi+lo tiles (128x32 bf16 = 8KB each) via global_load_lds width=16
#pragma unroll
        for (int j = 0; j < 2; ++j) {
            const int chunk = j * 4 + w;          // 0..7, wave-uniform
            const int r     = chunk * 16 + l4;    // tile row 0..127
            const long gA   = (bm + r) * (long)K + k0 + c8;
            const long gB   = (bn + r) * (long)K + k0 + c8;
            const int lbase = chunk * 512;        // elements (1024B per wave-issue)
            cp16(&sA[0][lbase], Ah + gA);
            cp16(&sA[1][lbase], Al + gA);
            cp16(&sB[0][lbase], Bh + gB);
            cp16(&sB[1][lbase], Bl + gB);
        }
        __syncthreads();

        bf16x8_t fah[4], fal[4], fbh[4], fbl[4];
#pragma unroll
        for (int mi = 0; mi < 4; ++mi) {
            int row = wm * 64 + mi * 16 + ar;
            fah[mi] = *(const bf16x8_t*)&sA[0][row * 32 + kq];
            fal[mi] = *(const bf16x8_t*)&sA[1][row * 32 + kq];
        }
#pragma unroll
        for (int ni = 0; ni < 4; ++ni) {
            int row = wn * 64 + ni * 16 + ar;
            fbh[ni] = *(const bf16x8_t*)&sB[0][row * 32 + kq];
            fbl[ni] = *(const bf16x8_t*)&sB[1][row * 32 + kq];
        }
#pragma unroll
        for (int mi = 0; mi < 4; ++mi)
#pragma unroll
            for (int ni = 0; ni < 4; ++ni) {
                acc[mi][ni] = __builtin_amdgcn_mfma_f32_16x16x32_bf16(fah[mi], fbh[ni], acc[mi][ni], 0, 0, 0);
                acc[mi][ni] = __builtin_amdgcn_mfma_f32_16x16x32_bf16(fah[mi], fbl[ni], acc[mi][ni], 0, 0, 0);
                acc[mi][ni] = __builtin_amdgcn_mfma_f32_16x16x32_bf16(fal[mi], fbh[ni], acc[mi][ni], 0, 0, 0);
            }
        __syncthreads();
    }

    // epilogue: D mapping col = lane&15, row = (lane>>4)*4 + reg  [m89-verified]
    const int col = lane & 15;
    const int rq  = (lane >> 4) << 2;
#pragma unroll
    for (int mi = 0; mi < 4; ++mi)
#pragma unroll
        for (int ni = 0; ni < 4; ++ni) {
            long mb = bm + wm * 64 + mi * 16 + rq;
            long nb = bn + wn * 64 + ni * 16 + col;
#pragma unroll
            for (int r = 0; r < 4; ++r) C[(mb + r) * (long)ldc + nb] = acc[mi][ni][r];
        }
}

// ---------------- causal depthwise conv (K=4) + SiLU ----------------
__global__ void k_conv(const float* __restrict__ proj, const float* __restrict__ cw,
                       const float* __restrict__ cb, float* __restrict__ xbc) {
    int c = blockIdx.x * 256 + threadIdx.x;
    int t = blockIdx.y;
    if (c >= CONVD) return;
    float acc = cb[c];
#pragma unroll
    for (int k = 0; k < 4; ++k) {
        int tt = t - 3 + k;
        if (tt >= 0) acc += proj[(size_t)tt * LDPROJ + INTER + c] * cw[c * 4 + k];
    }
    float s = acc / (1.f + expf(-acc));
    xbc[(size_t)t * CONVD + c] = s;
}

// ---------------- dt = softplus(raw + bias); dA = exp(-exp(A_log)*dt) ------------
__global__ void k_dt(const float* __restrict__ proj, const float* __restrict__ dtb,
                     const float* __restrict__ alog, float* __restrict__ dt,
                     float* __restrict__ dA) {
    int i = blockIdx.x * 256 + threadIdx.x;
    if (i >= SEQLEN * NHEADS) return;
    int t = i >> 6, h = i & 63;
    float raw = proj[(size_t)t * LDPROJ + 8320 + h] + dtb[h];
    float sp  = (raw > 20.f) ? raw : log1pf(expf(raw));
    dt[i] = sp;
    dA[i] = expf(-expf(alog[h]) * sp);
}

// ---------------- sequential SSM scan: wave per (head,p), lane = state n ----------
__global__ __launch_bounds__(256)
void k_scan(const float* __restrict__ xbc, const float* __restrict__ dt,
            const float* __restrict__ dA, const float* __restrict__ Dp,
            float* __restrict__ y) {
    __shared__ float Bs[64 * 64];
    __shared__ float Cs[64 * 64];
    const int tid  = threadIdx.x;
    const int lane = tid & 63;
    const int wid  = blockIdx.x * 4 + (tid >> 6);  // 0..4095
    const int h    = wid >> 6;
    const float Dv = Dp[h];
    float s = 0.f;

    for (int ch = 0; ch < SEQLEN / 64; ++ch) {
        const int t0 = ch * 64;
        // stage B,C (shared across all heads: GROUPS=1) for 64 timesteps
        for (int i = tid; i < 4096; i += 256) {
            int tt = i >> 6, n = i & 63;
            Bs[i] = xbc[(size_t)(t0 + tt) * CONVD + INTER + n];
            Cs[i] = xbc[(size_t)(t0 + tt) * CONVD + INTER + 64 + n];
        }
        __syncthreads();
        for (int tt = 0; tt < 64; ++tt) {
            const int t  = t0 + tt;
            float dAv = dA[t * 64 + h];
            float dtv = dt[t * 64 + h];
            float xv  = xbc[(size_t)t * CONVD + wid];   // x[t, h*64+p] (wid == h*64+p)
            s = dAv * s + (dtv * xv) * Bs[tt * 64 + lane];
            float yv = s * Cs[tt * 64 + lane];
#pragma unroll
            for (int off = 1; off < 64; off <<= 1) yv += __shfl_xor(yv, off, 64);
            if (lane == 0) y[(size_t)t * INTER + wid] = yv + Dv * xv;
        }
        __syncthreads();
    }
}

// ---------------- RMSNorm * silu(gate), then split to bf16 hi/lo ----------------
__global__ __launch_bounds__(256)
void k_norm(const float* __restrict__ y, const float* __restrict__ proj,
            const float* __restrict__ nw, unsigned short* __restrict__ ygh,
            unsigned short* __restrict__ ygl) {
    __shared__ float red[4];
    const int t = blockIdx.x, tid = threadIdx.x;
    float sum = 0.f;
    for (int i = tid; i < INTER; i += 256) {
        float v = y[(size_t)t * INTER + i];
        sum += v * v;
    }
#pragma unroll
    for (int off = 32; off >= 1; off >>= 1) sum += __shfl_xor(sum, off, 64);
    if ((tid & 63) == 0) red[tid >> 6] = sum;
    __syncthreads();
    float var = (red[0] + red[1] + red[2] + red[3]) * (1.f / INTER);
    float rs  = rsqrtf(var + 1e-6f);
    for (int i = tid; i < INTER; i += 256) {
        float v = y[(size_t)t * INTER + i] * rs * nw[i];
        float g = proj[(size_t)t * LDPROJ + i];
        float o = v * (g / (1.f + expf(-g)));
        __hip_bfloat16 hh = __float2bfloat16(o);
        float hf = __bfloat162float(hh);
        __hip_bfloat16 ll = __float2bfloat16(o - hf);
        ygh[(size_t)t * INTER + i] = *reinterpret_cast<unsigned short*>(&hh);
        ygl[(size_t)t * INTER + i] = *reinterpret_cast<unsigned short*>(&ll);
    }
}

// ---------------- workspace layout (bytes, all 256-aligned) ----------------
// region0 (16.78MB): hs_hi + hs_lo; reused later as ygh
// region1 (69.2MB):  w1_hi + w1_lo; reused later as w2_hi + w2_lo (after gemm1)
#define OFF_HSHI  ((size_t)0)
#define OFF_HSLO  ((size_t)8388608)
#define OFF_YGH   ((size_t)0)
#define OFF_W1HI  ((size_t)16777216)
#define OFF_W1LO  ((size_t)(16777216 + 34603008))
#define OFF_W2HI  ((size_t)16777216)
#define OFF_W2LO  ((size_t)(16777216 + 16777216))
#define OFF_PROJ  ((size_t)(16777216 + 69206016))            // 85983232
#define OFF_XBC   ((size_t)(85983232 + 69206016))            // 155189248
#define OFF_DT    ((size_t)(155189248 + 34603008))           // 189792256
#define OFF_DA    ((size_t)(189792256 + 524288))             // 190316544
#define OFF_Y     ((size_t)(190316544 + 524288))             // 190840832
#define OFF_YGL   ((size_t)(190840832 + 33554432))           // 224395264
// total: 241172480 bytes (~230 MB)

extern "C" void kernel_launch(void* const* d_in, const int* in_sizes, int n_in,
                              void* d_out, int out_size, void* d_ws, size_t ws_size,
                              hipStream_t stream) {
    (void)in_sizes; (void)n_in; (void)out_size; (void)ws_size;
    const float* hs   = (const float*)d_in[0];
    const float* w1   = (const float*)d_in[1];
    const float* cw   = (const float*)d_in[2];
    const float* cb   = (const float*)d_in[3];
    const float* dtb  = (const float*)d_in[4];
    const float* alog = (const float*)d_in[5];
    const float* Dp   = (const float*)d_in[6];
    const float* nw   = (const float*)d_in[7];
    const float* w2   = (const float*)d_in[8];
    float* out = (float*)d_out;
    char* ws = (char*)d_ws;

    unsigned short* hs_hi = (unsigned short*)(ws + OFF_HSHI);
    unsigned short* hs_lo = (unsigned short*)(ws + OFF_HSLO);
    unsigned short* w1_hi = (unsigned short*)(ws + OFF_W1HI);
    unsigned short* w1_lo = (unsigned short*)(ws + OFF_W1LO);
    unsigned short* w2_hi = (unsigned short*)(ws + OFF_W2HI);
    unsigned short* w2_lo = (unsigned short*)(ws + OFF_W2LO);
    unsigned short* ygh   = (unsigned short*)(ws + OFF_YGH);
    unsigned short* ygl   = (unsigned short*)(ws + OFF_YGL);
    float* proj = (float*)(ws + OFF_PROJ);
    float* xbc  = (float*)(ws + OFF_XBC);
    float* dtv  = (float*)(ws + OFF_DT);
    float* dAv  = (float*)(ws + OFF_DA);
    float* y    = (float*)(ws + OFF_Y);

    // 1) split inputs to bf16 hi/lo
    k_split<<<16384, 256, 0, stream>>>(hs, hs_hi, hs_lo, 4194304L, 4194304L);
    k_split<<<67584, 256, 0, stream>>>(w1, w1_hi, w1_lo, 17170432L, 17301504L); // pad rows 8384..8447 = 0

    // 2) in_proj: proj[2048 x 8448] = hs[2048x2048] @ w1[8448x2048]^T
    k_gemm_split<<<dim3(66, 16), 256, 0, stream>>>(hs_hi, hs_lo, w1_hi, w1_lo, proj, HIDDEN, LDPROJ);

    // 3) conv + silu on hBC columns; dt/dA
    k_conv<<<dim3(17, SEQLEN), 256, 0, stream>>>(proj, cw, cb, xbc);
    k_dt<<<512, 256, 0, stream>>>(proj, dtb, alog, dtv, dAv);

    // 4) sequential SSM scan
    k_scan<<<1024, 256, 0, stream>>>(xbc, dtv, dAv, Dp, y);

    // 5) RMSNorm * silu(gate) + split to bf16 (overwrites hs region with ygh)
    k_norm<<<SEQLEN, 256, 0, stream>>>(y, proj, nw, ygh, ygl);

    // 6) split out_proj weights (reuses w1 region — gemm1 already done)
    k_split<<<32768, 256, 0, stream>>>(w2, w2_hi, w2_lo, 8388608L, 8388608L);

    // 7) out = yg[2048x4096] @ w2[2048x4096]^T
    k_gemm_split<<<dim3(16, 16), 256, 0, stream>>>(ygh, ygl, w2_hi, w2_lo, out, INTER, HIDDEN);
}

// Round 2
// 770.684 us; speedup vs baseline: 2.2717x; 2.2717x over previous
//
#include <hip/hip_runtime.h>
#include <hip/hip_bf16.h>
#include <cstdint>
#include <cstddef>

// Problem constants
#define SEQLEN   2048
#define HIDDEN   2048
#define INTER    4096
#define NHEADS   64
#define NSTATE   64
#define CONVD    4224          // INTER + 2*64
#define LDPROJ   8448          // PROJ (8384) padded to 128-multiple
#define NCHUNK   32
#define CHUNK    64

typedef __attribute__((ext_vector_type(8))) short bf16x8_t;
typedef __attribute__((ext_vector_type(4))) float f32x4_t;

__device__ __forceinline__ void cp16(void* lds, const void* g) {
    __builtin_amdgcn_global_load_lds(
        (const __attribute__((address_space(1))) unsigned int*)g,
        (__attribute__((address_space(3))) unsigned int*)lds, 16, 0, 0);
}

// ---------------- split fp32 -> bf16 (hi, lo) ----------------
__global__ void k_split(const float* __restrict__ in, unsigned short* __restrict__ hi,
                        unsigned short* __restrict__ lo, long nvalid, long ntotal) {
    long i = (long)blockIdx.x * 256 + threadIdx.x;
    if (i >= ntotal) return;
    float x = (i < nvalid) ? in[i] : 0.0f;
    __hip_bfloat16 h = __float2bfloat16(x);
    float hf = __bfloat162float(h);
    __hip_bfloat16 l = __float2bfloat16(x - hf);
    hi[i] = *reinterpret_cast<unsigned short*>(&h);
    lo[i] = *reinterpret_cast<unsigned short*>(&l);
}

// ---------------- split-bf16 GEMM: C[M,N] = A[M,K] * B[N,K]^T (fp32-accurate) --------
__global__ __launch_bounds__(256, 2)
void k_gemm_split(const unsigned short* __restrict__ Ah, const unsigned short* __restrict__ Al,
                  const unsigned short* __restrict__ Bh, const unsigned short* __restrict__ Bl,
                  float* __restrict__ C, int K, int ldc) {
    __shared__ unsigned short sA[2][128 * 32];
    __shared__ unsigned short sB[2][128 * 32];

    const int tid  = threadIdx.x;
    const int lane = tid & 63;
    const int w    = tid >> 6;
    const int wm   = w >> 1, wn = w & 1;
    const long bm  = (long)blockIdx.y * 128;
    const long bn  = (long)blockIdx.x * 128;

    f32x4_t acc[4][4];
#pragma unroll
    for (int i = 0; i < 4; ++i)
#pragma unroll
        for (int j = 0; j < 4; ++j) acc[i][j] = (f32x4_t){0.f, 0.f, 0.f, 0.f};

    const int l4 = lane >> 2;
    const int c8 = (lane & 3) << 3;
    const int ar = lane & 15;
    const int kq = (lane >> 4) << 3;

    for (int k0 = 0; k0 < K; k0 += 32) {
#pragma unroll
        for (int j = 0; j < 2; ++j) {
            const int chunk = j * 4 + w;
            const int r     = chunk * 16 + l4;
            const long gA   = (bm + r) * (long)K + k0 + c8;
            const long gB   = (bn + r) * (long)K + k0 + c8;
            const int lbase = chunk * 512;
            cp16(&sA[0][lbase], Ah + gA);
            cp16(&sA[1][lbase], Al + gA);
            cp16(&sB[0][lbase], Bh + gB);
            cp16(&sB[1][lbase], Bl + gB);
        }
        __syncthreads();

        bf16x8_t fah[4], fal[4], fbh[4], fbl[4];
#pragma unroll
        for (int mi = 0; mi < 4; ++mi) {
            int row = wm * 64 + mi * 16 + ar;
            fah[mi] = *(const bf16x8_t*)&sA[0][row * 32 + kq];
            fal[mi] = *(const bf16x8_t*)&sA[1][row * 32 + kq];
        }
#pragma unroll
        for (int ni = 0; ni < 4; ++ni) {
            int row = wn * 64 + ni * 16 + ar;
            fbh[ni] = *(const bf16x8_t*)&sB[0][row * 32 + kq];
            fbl[ni] = *(const bf16x8_t*)&sB[1][row * 32 + kq];
        }
#pragma unroll
        for (int mi = 0; mi < 4; ++mi)
#pragma unroll
            for (int ni = 0; ni < 4; ++ni) {
                acc[mi][ni] = __builtin_amdgcn_mfma_f32_16x16x32_bf16(fah[mi], fbh[ni], acc[mi][ni], 0, 0, 0);
                acc[mi][ni] = __builtin_amdgcn_mfma_f32_16x16x32_bf16(fah[mi], fbl[ni], acc[mi][ni], 0, 0, 0);
                acc[mi][ni] = __builtin_amdgcn_mfma_f32_16x16x32_bf16(fal[mi], fbh[ni], acc[mi][ni], 0, 0, 0);
            }
        __syncthreads();
    }

    const int col = lane & 15;
    const int rq  = (lane >> 4) << 2;
#pragma unroll
    for (int mi = 0; mi < 4; ++mi)
#pragma unroll
        for (int ni = 0; ni < 4; ++ni) {
            long mb = bm + wm * 64 + mi * 16 + rq;
            long nb = bn + wn * 64 + ni * 16 + col;
#pragma unroll
            for (int r = 0; r < 4; ++r) C[(mb + r) * (long)ldc + nb] = acc[mi][ni][r];
        }
}

// ---------------- causal depthwise conv (K=4) + SiLU ----------------
__global__ void k_conv(const float* __restrict__ proj, const float* __restrict__ cw,
                       const float* __restrict__ cb, float* __restrict__ xbc) {
    int c = blockIdx.x * 256 + threadIdx.x;
    int t = blockIdx.y;
    if (c >= CONVD) return;
    float acc = cb[c];
#pragma unroll
    for (int k = 0; k < 4; ++k) {
        int tt = t - 3 + k;
        if (tt >= 0) acc += proj[(size_t)tt * LDPROJ + INTER + c] * cw[c * 4 + k];
    }
    float s = acc / (1.f + expf(-acc));
    xbc[(size_t)t * CONVD + c] = s;
}

// ---------------- dt = softplus(raw + bias); cd = within-chunk inclusive cumsum ----
__global__ __launch_bounds__(256)
void k_cum(const float* __restrict__ proj, const float* __restrict__ dtb,
           float* __restrict__ dt, float* __restrict__ cd) {
    const int tid  = threadIdx.x;
    const int lane = tid & 63;
    const int wid  = blockIdx.x * 4 + (tid >> 6);   // 0..2047
    const int c    = wid >> 6;                       // chunk
    const int h    = wid & 63;                       // head
    const int t    = c * CHUNK + lane;
    float raw = proj[(size_t)t * LDPROJ + 8320 + h] + dtb[h];
    float sp  = (raw > 20.f) ? raw : log1pf(expf(raw));
    float x = sp;
#pragma unroll
    for (int off = 1; off < 64; off <<= 1) {
        float v = __shfl_up(x, off, 64);
        if (lane >= off) x += v;
    }
    dt[t * 64 + h] = sp;
    cd[t * 64 + h] = x;
}

// ---------------- SSD intra-chunk: G = tril(CB^T ∘ decay), Y=G@X, M=(wB)^T@X ------
// one block per (chunk, head); 256 threads as 16x16 grid of 4x4 register tiles
__global__ __launch_bounds__(256, 2)
void k_ssdA(const float* __restrict__ xbc, const float* __restrict__ dt,
            const float* __restrict__ cd, const float* __restrict__ alog,
            const float* __restrict__ Dp, float* __restrict__ y,
            float* __restrict__ M) {
    __shared__ float Xs[64][68];
    __shared__ float Bs[64][68];
    __shared__ float Cs[64][68];   // reused as Gs after G computed
    __shared__ float dts[64], cds[64], wts[64];
    float (*Gs)[68] = Cs;

    const int c = blockIdx.x, h = blockIdx.y;
    const int tid = threadIdx.x;
    const int tr = tid >> 4, tc = tid & 15;
    const int t0 = c * CHUNK;
    const float A = -__expf(alog[h]);

    for (int i = tid; i < 4096; i += 256) {
        int t = i >> 6, j = i & 63;
        size_t base = (size_t)(t0 + t) * CONVD;
        Xs[t][j] = xbc[base + h * 64 + j];
        Bs[t][j] = xbc[base + INTER + j];
        Cs[t][j] = xbc[base + INTER + 64 + j];
    }
    if (tid < 64) {
        dts[tid] = dt[(t0 + tid) * 64 + h];
        cds[tid] = cd[(t0 + tid) * 64 + h];
    }
    __syncthreads();
    if (tid < 64) wts[tid] = __expf(A * (cds[63] - cds[tid])) * dts[tid];

    // ---- G accumulation: rows t=4tr+i, cols tau=4tc+j, k over n ----
    float g[4][4];
#pragma unroll
    for (int i = 0; i < 4; ++i)
#pragma unroll
        for (int j = 0; j < 4; ++j) g[i][j] = 0.f;
    for (int n = 0; n < 64; n += 4) {
        float4 cv[4], bv[4];
#pragma unroll
        for (int i = 0; i < 4; ++i) cv[i] = *(const float4*)&Cs[tr * 4 + i][n];
#pragma unroll
        for (int j = 0; j < 4; ++j) bv[j] = *(const float4*)&Bs[tc * 4 + j][n];
#pragma unroll
        for (int i = 0; i < 4; ++i)
#pragma unroll
            for (int j = 0; j < 4; ++j)
                g[i][j] += cv[i].x * bv[j].x + cv[i].y * bv[j].y +
                           cv[i].z * bv[j].z + cv[i].w * bv[j].w;
    }
    __syncthreads();   // everyone done reading Cs before overwrite with Gs
#pragma unroll
    for (int i = 0; i < 4; ++i) {
        int t = tr * 4 + i;
#pragma unroll
        for (int j = 0; j < 4; ++j) {
            int tau = tc * 4 + j;
            float v = (tau <= t) ? g[i][j] * __expf(A * (cds[t] - cds[tau])) * dts[tau] : 0.f;
            Gs[t][tau] = v;
        }
    }
    __syncthreads();

    // ---- Y_intra = G @ X  (+ D*x), rows t, cols p; and M = (w.B)^T @ X ----
    float accY[4][4], accM[4][4];
#pragma unroll
    for (int i = 0; i < 4; ++i)
#pragma unroll
        for (int j = 0; j < 4; ++j) { accY[i][j] = 0.f; accM[i][j] = 0.f; }

    for (int tau = 0; tau < 64; tau += 4) {
        float4 gv[4], xv[4];
#pragma unroll
        for (int i = 0; i < 4; ++i) gv[i] = *(const float4*)&Gs[tr * 4 + i][tau];
#pragma unroll
        for (int k = 0; k < 4; ++k) xv[k] = *(const float4*)&Xs[tau + k][tc * 4];
#pragma unroll
        for (int i = 0; i < 4; ++i) {
            accY[i][0] += gv[i].x * xv[0].x + gv[i].y * xv[1].x + gv[i].z * xv[2].x + gv[i].w * xv[3].x;
            accY[i][1] += gv[i].x * xv[0].y + gv[i].y * xv[1].y + gv[i].z * xv[2].y + gv[i].w * xv[3].y;
            accY[i][2] += gv[i].x * xv[0].z + gv[i].y * xv[1].z + gv[i].z * xv[2].z + gv[i].w * xv[3].z;
            accY[i][3] += gv[i].x * xv[0].w + gv[i].y * xv[1].w + gv[i].z * xv[2].w + gv[i].w * xv[3].w;
        }
        // M: rows n=4tr+i, cols p=4tc+j, accumulate over these 4 tau
#pragma unroll
        for (int k = 0; k < 4; ++k) {
            float w = wts[tau + k];
            float4 bv = *(const float4*)&Bs[tau + k][tr * 4];
            float4 xk = xv[k];
            float wb0 = w * bv.x, wb1 = w * bv.y, wb2 = w * bv.z, wb3 = w * bv.w;
            accM[0][0] += wb0 * xk.x; accM[0][1] += wb0 * xk.y; accM[0][2] += wb0 * xk.z; accM[0][3] += wb0 * xk.w;
            accM[1][0] += wb1 * xk.x; accM[1][1] += wb1 * xk.y; accM[1][2] += wb1 * xk.z; accM[1][3] += wb1 * xk.w;
            accM[2][0] += wb2 * xk.x; accM[2][1] += wb2 * xk.y; accM[2][2] += wb2 * xk.z; accM[2][3] += wb2 * xk.w;
            accM[3][0] += wb3 * xk.x; accM[3][1] += wb3 * xk.y; accM[3][2] += wb3 * xk.z; accM[3][3] += wb3 * xk.w;
        }
    }

    const float Dv = Dp[h];
#pragma unroll
    for (int i = 0; i < 4; ++i) {
        int t = tr * 4 + i;
        float4 o;
        o.x = accY[i][0] + Dv * Xs[t][tc * 4 + 0];
        o.y = accY[i][1] + Dv * Xs[t][tc * 4 + 1];
        o.z = accY[i][2] + Dv * Xs[t][tc * 4 + 2];
        o.w = accY[i][3] + Dv * Xs[t][tc * 4 + 3];
        *(float4*)&y[(size_t)(t0 + t) * INTER + h * 64 + tc * 4] = o;
    }
    size_t mbase = ((size_t)(c * 64 + h)) << 12;   // [c][h][n][p]
#pragma unroll
    for (int i = 0; i < 4; ++i) {
        float4 o = { accM[i][0], accM[i][1], accM[i][2], accM[i][3] };
        *(float4*)&M[mbase + (size_t)(tr * 4 + i) * 64 + tc * 4] = o;
    }
}

// ---------------- sequential chunk-state propagation ----------------
__global__ __launch_bounds__(256)
void k_state(const float* __restrict__ M, const float* __restrict__ cd,
             const float* __restrict__ alog, float* __restrict__ Sprev) {
    const int g  = blockIdx.x * 256 + threadIdx.x;   // 0..262143
    const int h  = g >> 12;
    const int np = g & 4095;
    const float A = -__expf(alog[h]);
    float s = 0.f;
#pragma unroll 1
    for (int c = 0; c < NCHUNK; ++c) {
        size_t idx = (((size_t)(c * 64 + h)) << 12) + np;
        Sprev[idx] = s;
        float decay = __expf(A * cd[((c * CHUNK + 63) * 64) + h]);
        s = decay * s + M[idx];
    }
}

// ---------------- SSD inter-chunk: y += exp(A*cd_t) * C_t . S_prev ----------------
__global__ __launch_bounds__(256, 2)
void k_ssdC(const float* __restrict__ xbc, const float* __restrict__ cd,
            const float* __restrict__ alog, const float* __restrict__ Sprev,
            float* __restrict__ y) {
    __shared__ float Ss[64][68];   // [n][p]
    __shared__ float Cs[64][68];   // [t][n]
    __shared__ float cds[64];
    const int c = blockIdx.x, h = blockIdx.y;
    const int tid = threadIdx.x;
    const int tr = tid >> 4, tc = tid & 15;
    const int t0 = c * CHUNK;
    const float A = -__expf(alog[h]);

    size_t sbase = ((size_t)(c * 64 + h)) << 12;
    for (int i = tid; i < 4096; i += 256) {
        int n = i >> 6, p = i & 63;
        Ss[n][p] = Sprev[sbase + i];
        Cs[n][p] = xbc[(size_t)(t0 + n) * CONVD + INTER + 64 + p];  // [t][n] reuse loop
    }
    if (tid < 64) cds[tid] = cd[(t0 + tid) * 64 + h];
    __syncthreads();

    float acc[4][4];
#pragma unroll
    for (int i = 0; i < 4; ++i)
#pragma unroll
        for (int j = 0; j < 4; ++j) acc[i][j] = 0.f;

    for (int n = 0; n < 64; n += 4) {
        float4 cv[4], sv[4];
#pragma unroll
        for (int i = 0; i < 4; ++i) cv[i] = *(const float4*)&Cs[tr * 4 + i][n];
#pragma unroll
        for (int k = 0; k < 4; ++k) sv[k] = *(const float4*)&Ss[n + k][tc * 4];
#pragma unroll
        for (int i = 0; i < 4; ++i) {
            acc[i][0] += cv[i].x * sv[0].x + cv[i].y * sv[1].x + cv[i].z * sv[2].x + cv[i].w * sv[3].x;
            acc[i][1] += cv[i].x * sv[0].y + cv[i].y * sv[1].y + cv[i].z * sv[2].y + cv[i].w * sv[3].y;
            acc[i][2] += cv[i].x * sv[0].z + cv[i].y * sv[1].z + cv[i].z * sv[2].z + cv[i].w * sv[3].z;
            acc[i][3] += cv[i].x * sv[0].w + cv[i].y * sv[1].w + cv[i].z * sv[2].w + cv[i].w * sv[3].w;
        }
    }

#pragma unroll
    for (int i = 0; i < 4; ++i) {
        int t = tr * 4 + i;
        float sc = __expf(A * cds[t]);
        size_t yi = (size_t)(t0 + t) * INTER + h * 64 + tc * 4;
        float4 cur = *(const float4*)&y[yi];
        cur.x += sc * acc[i][0];
        cur.y += sc * acc[i][1];
        cur.z += sc * acc[i][2];
        cur.w += sc * acc[i][3];
        *(float4*)&y[yi] = cur;
    }
}

// ---------------- RMSNorm * silu(gate), then split to bf16 hi/lo ----------------
__global__ __launch_bounds__(256)
void k_norm(const float* __restrict__ y, const float* __restrict__ proj,
            const float* __restrict__ nw, unsigned short* __restrict__ ygh,
            unsigned short* __restrict__ ygl) {
    __shared__ float red[4];
    const int t = blockIdx.x, tid = threadIdx.x;
    float sum = 0.f;
    for (int i = tid; i < INTER; i += 256) {
        float v = y[(size_t)t * INTER + i];
        sum += v * v;
    }
#pragma unroll
    for (int off = 32; off >= 1; off >>= 1) sum += __shfl_xor(sum, off, 64);
    if ((tid & 63) == 0) red[tid >> 6] = sum;
    __syncthreads();
    float var = (red[0] + red[1] + red[2] + red[3]) * (1.f / INTER);
    float rs  = rsqrtf(var + 1e-6f);
    for (int i = tid; i < INTER; i += 256) {
        float v = y[(size_t)t * INTER + i] * rs * nw[i];
        float g = proj[(size_t)t * LDPROJ + i];
        float o = v * (g / (1.f + expf(-g)));
        __hip_bfloat16 hh = __float2bfloat16(o);
        float hf = __bfloat162float(hh);
        __hip_bfloat16 ll = __float2bfloat16(o - hf);
        ygh[(size_t)t * INTER + i] = *reinterpret_cast<unsigned short*>(&hh);
        ygl[(size_t)t * INTER + i] = *reinterpret_cast<unsigned short*>(&ll);
    }
}

// ---------------- workspace layout (bytes) ----------------
// [0,16MB): hs hi/lo -> later ygh
// [16MB,86MB): w1 hi/lo -> later M (33.5MB) + Sprev (33.5MB) -> later w2 hi/lo (32MB)
#define OFF_HSHI  ((size_t)0)
#define OFF_HSLO  ((size_t)8388608)
#define OFF_YGH   ((size_t)0)
#define OFF_W1HI  ((size_t)16777216)
#define OFF_W1LO  ((size_t)(16777216 + 34603008))
#define OFF_M     ((size_t)16777216)
#define OFF_SPREV ((size_t)50331648)
#define OFF_W2HI  ((size_t)16777216)
#define OFF_W2LO  ((size_t)33554432)
#define OFF_PROJ  ((size_t)85983232)
#define OFF_XBC   ((size_t)155189248)
#define OFF_DT    ((size_t)189792256)
#define OFF_CD    ((size_t)190316544)
#define OFF_Y     ((size_t)190840832)
#define OFF_YGL   ((size_t)224395264)
// total: 241172480 bytes (~230 MB) — same footprint as round 1

extern "C" void kernel_launch(void* const* d_in, const int* in_sizes, int n_in,
                              void* d_out, int out_size, void* d_ws, size_t ws_size,
                              hipStream_t stream) {
    (void)in_sizes; (void)n_in; (void)out_size; (void)ws_size;
    const float* hs   = (const float*)d_in[0];
    const float* w1   = (const float*)d_in[1];
    const float* cw   = (const float*)d_in[2];
    const float* cb   = (const float*)d_in[3];
    const float* dtb  = (const float*)d_in[4];
    const float* alog = (const float*)d_in[5];
    const float* Dp   = (const float*)d_in[6];
    const float* nw   = (const float*)d_in[7];
    const float* w2   = (const float*)d_in[8];
    float* out = (float*)d_out;
    char* ws = (char*)d_ws;

    unsigned short* hs_hi = (unsigned short*)(ws + OFF_HSHI);
    unsigned short* hs_lo = (unsigned short*)(ws + OFF_HSLO);
    unsigned short* w1_hi = (unsigned short*)(ws + OFF_W1HI);
    unsigned short* w1_lo = (unsigned short*)(ws + OFF_W1LO);
    unsigned short* w2_hi = (unsigned short*)(ws + OFF_W2HI);
    unsigned short* w2_lo = (unsigned short*)(ws + OFF_W2LO);
    unsigned short* ygh   = (unsigned short*)(ws + OFF_YGH);
    unsigned short* ygl   = (unsigned short*)(ws + OFF_YGL);
    float* proj  = (float*)(ws + OFF_PROJ);
    float* xbc   = (float*)(ws + OFF_XBC);
    float* dtv   = (float*)(ws + OFF_DT);
    float* cdv   = (float*)(ws + OFF_CD);
    float* y     = (float*)(ws + OFF_Y);
    float* M     = (float*)(ws + OFF_M);
    float* Sprev = (float*)(ws + OFF_SPREV);

    // 1) split inputs to bf16 hi/lo
    k_split<<<16384, 256, 0, stream>>>(hs, hs_hi, hs_lo, 4194304L, 4194304L);
    k_split<<<67584, 256, 0, stream>>>(w1, w1_hi, w1_lo, 17170432L, 17301504L);

    // 2) in_proj: proj[2048 x 8448] = hs @ w1^T
    k_gemm_split<<<dim3(66, 16), 256, 0, stream>>>(hs_hi, hs_lo, w1_hi, w1_lo, proj, HIDDEN, LDPROJ);

    // 3) conv + silu; dt softplus + within-chunk cumsum
    k_conv<<<dim3(17, SEQLEN), 256, 0, stream>>>(proj, cw, cb, xbc);
    k_cum<<<512, 256, 0, stream>>>(proj, dtb, dtv, cdv);

    // 4) chunked SSD (replaces sequential scan)
    k_ssdA<<<dim3(NCHUNK, NHEADS), 256, 0, stream>>>(xbc, dtv, cdv, alog, Dp, y, M);
    k_state<<<1024, 256, 0, stream>>>(M, cdv, alog, Sprev);
    k_ssdC<<<dim3(NCHUNK, NHEADS), 256, 0, stream>>>(xbc, cdv, alog, Sprev, y);

    // 5) RMSNorm * silu(gate) + split to bf16
    k_norm<<<SEQLEN, 256, 0, stream>>>(y, proj, nw, ygh, ygl);

    // 6) split out_proj weights (reuses w1/M region — both dead by now)
    k_split<<<32768, 256, 0, stream>>>(w2, w2_hi, w2_lo, 8388608L, 8388608L);

    // 7) out = yg[2048x4096] @ w2[2048x4096]^T
    k_gemm_split<<<dim3(16, 16), 256, 0, stream>>>(ygh, ygl, w2_hi, w2_lo, out, INTER, HIDDEN);
}